// Round 1
// baseline (198.145 us; speedup 1.0000x reference)
//
#include <hip/hip_runtime.h>

typedef unsigned long long u64;

#define HW   3136      // 56*56
#define CIN  256
#define CMID 768
#define EPSV 1e-5

// ---------------------------------------------------------------------------
// prep: pack weight sign bits (bit=1 <=> w<0) and fold BN into A*p+B form.
//   layer1: y1bn = p1*A1[o] + B1[o],  p1 = popc(w_row XOR x_bits)
//           A1 = -2*inv1, B1 = 256*inv1 + (beta1 - mean1*inv1)
//   layer2: y2bn = p2*A2[o] + B2[o],  A2 = -2*inv2, B2 = 768*inv2 + bias2
// ---------------------------------------------------------------------------
__global__ __launch_bounds__(64) void prep_kernel(
    const float* __restrict__ w1, const float* __restrict__ w2,
    const float* __restrict__ g1, const float* __restrict__ b1,
    const float* __restrict__ m1, const float* __restrict__ v1,
    const float* __restrict__ g2, const float* __restrict__ b2,
    const float* __restrict__ m2, const float* __restrict__ v2,
    u64* __restrict__ pw1, u64* __restrict__ pw2,
    float* __restrict__ A1, float* __restrict__ B1,
    float* __restrict__ A2, float* __restrict__ B2)
{
  int blk  = blockIdx.x;
  int lane = threadIdx.x;
  if (blk < 3072) {                       // w1: 768 rows x 4 words
    int o = blk >> 2, seg = blk & 3;
    float v = w1[o * CIN + (seg << 6) + lane];
    u64 msk = __ballot(v < 0.0f);
    if (lane == 0) pw1[blk] = msk;
  } else if (blk < 6144) {                // w2: 256 rows x 12 words
    int i = blk - 3072;
    int o = i / 12, seg = i - o * 12;
    float v = w2[o * CMID + (seg << 6) + lane];
    u64 msk = __ballot(v < 0.0f);
    if (lane == 0) pw2[i] = msk;
  } else {                                // BN constants (1024 entries)
    int i = ((blk - 6144) << 6) + lane;
    if (i < CMID) {
      double inv = (double)g1[i] / sqrt((double)v1[i] + EPSV);
      A1[i] = (float)(-2.0 * inv);
      B1[i] = (float)(256.0 * inv + (double)b1[i] - (double)m1[i] * inv);
    } else {
      int j = i - CMID;                   // 0..255
      double inv = (double)g2[j] / sqrt((double)v2[j] + EPSV);
      A2[j] = (float)(-2.0 * inv);
      B2[j] = (float)(768.0 * inv + (double)b2[j] - (double)m2[j] * inv);
    }
  }
}

// ---------------------------------------------------------------------------
// main: one thread per pixel. Pack sign(x) -> 4 u64, binary GEMV 768x256 via
// xor+popc against LDS-staged packed W1, BN+sign -> 12 u64, binary GEMV
// 256x768 against packed W2, BN, +x, store. Exact-zero channels of x are
// corrected via a zero-mask (slow path, ~3 threads in the whole grid).
// ---------------------------------------------------------------------------
__global__ __launch_bounds__(256) void bnn_kernel(
    const float* __restrict__ x,
    const u64* __restrict__ pw1, const u64* __restrict__ pw2,
    const float* __restrict__ A1g, const float* __restrict__ B1g,
    const float* __restrict__ A2g, const float* __restrict__ B2g,
    float* __restrict__ out)
{
  __shared__ u64  sw1[CMID * 4];          // 24 KB
  __shared__ u64  sw2[CIN * 12];          // 24 KB
  __shared__ float sA1[CMID], sB1[CMID];  // 6 KB
  __shared__ float sA2[CIN],  sB2[CIN];   // 2 KB

  int t = threadIdx.x;
  for (int i = t; i < CMID * 4;  i += 256) sw1[i] = pw1[i];
  for (int i = t; i < CIN * 12;  i += 256) sw2[i] = pw2[i];
  for (int i = t; i < CMID; i += 256) { sA1[i] = A1g[i]; sB1[i] = B1g[i]; }
  for (int i = t; i < CIN;  i += 256) { sA2[i] = A2g[i]; sB2[i] = B2g[i]; }
  __syncthreads();

  int pix = blockIdx.x * 256 + t;         // 392*256 == 100352 exactly
  int b  = pix / HW;
  int hw = pix - b * HW;
  const float* xp = x   + (size_t)b * (CIN * HW) + hw;
  float*       op = out + (size_t)b * (CIN * HW) + hw;

  // ---- pack sign bits of x (bit=1 <=> x<0), plus exact-zero mask ----
  u64 sx[4] = {0, 0, 0, 0};
  u64 zx[4] = {0, 0, 0, 0};
  #pragma unroll 8
  for (int c = 0; c < CIN; ++c) {
    float v = xp[(size_t)c * HW];
    unsigned u = __float_as_uint(v);
    sx[c >> 6] |= (u64)(u >> 31) << (c & 63);
    zx[c >> 6] |= (u64)(v == 0.0f ? 1u : 0u) << (c & 63);
  }
  bool hasZero = (zx[0] | zx[1] | zx[2] | zx[3]) != 0ull;

  // ---- layer 1: 768x256 binary GEMV + BN + sign-pack ----
  u64 sy[12];
  #pragma unroll
  for (int j = 0; j < 12; ++j) sy[j] = 0ull;

  if (!hasZero) {
    #pragma unroll 4
    for (int o = 0; o < CMID; ++o) {
      const u64* w = &sw1[o * 4];
      int p = __popcll(w[0] ^ sx[0]) + __popcll(w[1] ^ sx[1])
            + __popcll(w[2] ^ sx[2]) + __popcll(w[3] ^ sx[3]);
      float y = fmaf((float)p, sA1[o], sB1[o]);
      sy[o >> 6] |= (u64)(y < 0.0f ? 1u : 0u) << (o & 63);
    }
  } else {
    // exact path: drop contributions where x==0 (jnp.sign(0)==0)
    float K0h = 0.5f * (float)(__popcll(zx[0]) + __popcll(zx[1]) +
                               __popcll(zx[2]) + __popcll(zx[3]));
    for (int o = 0; o < CMID; ++o) {
      const u64* w = &sw1[o * 4];
      u64 d0 = w[0] ^ sx[0], d1 = w[1] ^ sx[1];
      u64 d2 = w[2] ^ sx[2], d3 = w[3] ^ sx[3];
      int p  = __popcll(d0) + __popcll(d1) + __popcll(d2) + __popcll(d3);
      int dz = __popcll(d0 & zx[0]) + __popcll(d1 & zx[1]) +
               __popcll(d2 & zx[2]) + __popcll(d3 & zx[3]);
      // y1_exact = (256-2p) - K0 + 2*dz ; in BN domain: + (K0/2 - dz)*A1
      float y = fmaf((float)p, sA1[o], sB1[o]) + (K0h - (float)dz) * sA1[o];
      sy[o >> 6] |= (u64)(y < 0.0f ? 1u : 0u) << (o & 63);
    }
  }

  // ---- layer 2: 256x768 binary GEMV + BN + residual ----
  #pragma unroll 4
  for (int o = 0; o < CIN; ++o) {
    const u64* w = &sw2[o * 12];
    int p = 0;
    #pragma unroll
    for (int j = 0; j < 12; ++j) p += __popcll(w[j] ^ sy[j]);
    float y = fmaf((float)p, sA2[o], sB2[o]);
    op[(size_t)o * HW] = y + xp[(size_t)o * HW];
  }
}

extern "C" void kernel_launch(void* const* d_in, const int* in_sizes, int n_in,
                              void* d_out, int out_size, void* d_ws, size_t ws_size,
                              hipStream_t stream) {
  const float* x  = (const float*)d_in[0];
  const float* w1 = (const float*)d_in[1];
  const float* w2 = (const float*)d_in[2];
  const float* g1 = (const float*)d_in[3];
  const float* b1 = (const float*)d_in[4];
  const float* m1 = (const float*)d_in[5];
  const float* v1 = (const float*)d_in[6];
  const float* g2 = (const float*)d_in[7];
  const float* b2 = (const float*)d_in[8];
  const float* m2 = (const float*)d_in[9];
  const float* v2 = (const float*)d_in[10];
  float* out = (float*)d_out;

  u64*   pw1 = (u64*)d_ws;
  u64*   pw2 = pw1 + 3072;
  float* A1  = (float*)(pw2 + 3072);
  float* B1  = A1 + CMID;
  float* A2  = B1 + CMID;
  float* B2  = A2 + CIN;

  prep_kernel<<<6160, 64, 0, stream>>>(w1, w2, g1, b1, m1, v1,
                                       g2, b2, m2, v2,
                                       pw1, pw2, A1, B1, A2, B2);
  bnn_kernel<<<392, 256, 0, stream>>>(x, pw1, pw2, A1, B1, A2, B2, out);
}

// Round 2
// 163.853 us; speedup vs baseline: 1.2093x; 1.2093x over previous
//
#include <hip/hip_runtime.h>

typedef unsigned long long u64;

#define HW    3136      // 56*56
#define CIN   256
#define CMID  768
#define EPSV  1e-5

__device__ __forceinline__ u64 shfl_xor64(u64 v, int m) {
  unsigned lo = (unsigned)__shfl_xor((int)(unsigned)v, m);
  unsigned hi = (unsigned)__shfl_xor((int)(v >> 32), m);
  return ((u64)hi << 32) | lo;
}

// ---------------------------------------------------------------------------
// prep: pack weight sign bits (bit=1 <=> w<0); layer-1 BN folded to integer
// threshold t1[o] (sign(y1bn)<0 <=> 2p > t1, p = popc mismatches);
// layer-2 BN folded to float2 (A2,B2): y2 = p*A2 + B2.
// ---------------------------------------------------------------------------
__global__ __launch_bounds__(64) void prep_kernel(
    const float* __restrict__ w1, const float* __restrict__ w2,
    const float* __restrict__ g1, const float* __restrict__ b1,
    const float* __restrict__ m1, const float* __restrict__ v1,
    const float* __restrict__ g2, const float* __restrict__ b2,
    const float* __restrict__ m2, const float* __restrict__ v2,
    u64* __restrict__ pw1, u64* __restrict__ pw2,
    int* __restrict__ t1, float2* __restrict__ ab2)
{
  int blk  = blockIdx.x;
  int lane = threadIdx.x;
  if (blk < 3072) {                       // w1: 768 rows x 4 words
    int o = blk >> 2, seg = blk & 3;
    u64 msk = __ballot(w1[o * CIN + (seg << 6) + lane] < 0.0f);
    if (lane == 0) pw1[blk] = msk;
  } else if (blk < 6144) {                // w2: 256 rows x 12 words
    int i = blk - 3072;
    int o = i / 12, seg = i - o * 12;
    u64 msk = __ballot(w2[o * CMID + (seg << 6) + lane] < 0.0f);
    if (lane == 0) pw2[i] = msk;
  } else {                                // BN constants
    int i = ((blk - 6144) << 6) + lane;
    if (i < CMID) {
      double inv = (double)g1[i] / sqrt((double)v1[i] + EPSV);
      double c   = (double)b1[i] - (double)m1[i] * inv;
      // y1bn < 0  <=>  2p > 256 + c/inv   (inv > 0 always)
      t1[i] = (int)floor(256.0 + c / inv);
    } else if (i < CMID + CIN) {
      int j = i - CMID;
      double inv = (double)g2[j] / sqrt((double)v2[j] + EPSV);
      float2 o2;
      o2.x = (float)(-2.0 * inv);
      o2.y = (float)(768.0 * inv + (double)b2[j] - (double)m2[j] * inv);
      ab2[j] = o2;
    }
  }
}

// ---------------------------------------------------------------------------
// rare path: pixel has an exact-zero input channel (jnp.sign(0)==0).
// Rebuild this thread's partial sign words exactly:
//   y1_exact = 256 - K0 - 2p + 2dz  ->  bit = (2p + K0 - 2dz) > t1[o]
// Quad-uniform divergence: all 4 split-lanes of a pixel take this together.
// ---------------------------------------------------------------------------
__device__ __forceinline__ void fix_px(const float* __restrict__ cxp,
                                       const u64 sx[4], u64 ps[12], int r,
                                       const u64* sw1, const int* st1)
{
  u64 zl = 0;
  for (int cl = 0; cl < 64; ++cl)
    zl |= (u64)(cxp[(size_t)cl * HW] == 0.0f ? 1u : 0u) << cl;
  u64 pm = shfl_xor64(zl, 1);
  u64 e0 = (r & 1) ? pm : zl, e1 = (r & 1) ? zl : pm;
  u64 f0 = shfl_xor64(e0, 2), f1 = shfl_xor64(e1, 2);
  u64 zx[4];
  zx[0] = (r & 2) ? f0 : e0; zx[1] = (r & 2) ? f1 : e1;
  zx[2] = (r & 2) ? e0 : f0; zx[3] = (r & 2) ? e1 : f1;
  int K0 = __popcll(zx[0]) + __popcll(zx[1]) + __popcll(zx[2]) + __popcll(zx[3]);
  #pragma unroll
  for (int wi = 0; wi < 12; ++wi) {
    u64 a = 0;
    for (int ii = 0; ii < 16; ++ii) {
      int o = (((wi << 4) | ii) << 2) | r;
      ulonglong2 wa = *(const ulonglong2*)&sw1[(size_t)(o << 2)];
      ulonglong2 wb = *(const ulonglong2*)&sw1[(size_t)(o << 2) + 2];
      u64 d0 = wa.x ^ sx[0], d1 = wa.y ^ sx[1];
      u64 d2 = wb.x ^ sx[2], d3 = wb.y ^ sx[3];
      int p  = __popcll(d0) + __popcll(d1) + __popcll(d2) + __popcll(d3);
      int dz = __popcll(d0 & zx[0]) + __popcll(d1 & zx[1]) +
               __popcll(d2 & zx[2]) + __popcll(d3 & zx[3]);
      a |= (u64)(unsigned)((p + p + K0 - dz - dz) > st1[o]) << ((ii << 2) | r);
    }
    ps[wi] = a;
  }
}

// ---------------------------------------------------------------------------
// main: 256 threads = 64 pixel-slots x 4 output-splits; each thread owns
// 2 pixels (slot q and q+64). Interleaved rows o=4i+r keep the quad's
// concurrent ds_read_b128 on distinct banks. sx/sy shared via shfl butterflies.
// ---------------------------------------------------------------------------
__global__ __launch_bounds__(256, 3) void bnn_kernel(
    const float* __restrict__ x,
    const u64* __restrict__ pw1, const u64* __restrict__ pw2,
    const int* __restrict__ t1g, const float2* __restrict__ ab2g,
    float* __restrict__ out)
{
  __shared__ __align__(16) u64 sw1[CMID * 4];   // 24 KB
  __shared__ __align__(16) u64 sw2[CIN * 12];   // 24 KB
  __shared__ int    st1[CMID];                  // 3 KB
  __shared__ float2 sab2[CIN];                  // 2 KB   total 54,272 B -> 3 blocks/CU

  int t = threadIdx.x;
  for (int i = t; i < CMID * 4; i += 256) sw1[i] = pw1[i];
  for (int i = t; i < CIN * 12; i += 256) sw2[i] = pw2[i];
  for (int i = t; i < CMID; i += 256) st1[i] = t1g[i];
  for (int i = t; i < CIN;  i += 256) sab2[i] = ab2g[i];
  __syncthreads();

  int r = t & 3;
  int q = t >> 2;
  int px0 = blockIdx.x * 128 + q;   // 784*128 == 100352 exactly
  int px1 = px0 + 64;
  int b0 = px0 / HW, hw0 = px0 - b0 * HW;
  int b1i = px1 / HW, hw1 = px1 - b1i * HW;
  const float* xp0 = x + (size_t)b0  * (CIN * HW) + hw0;
  const float* xp1 = x + (size_t)b1i * (CIN * HW) + hw1;
  float* op0 = out + (size_t)b0  * (CIN * HW) + hw0;
  float* op1 = out + (size_t)b1i * (CIN * HW) + hw1;

  // ---- pack: this thread packs channels [r*64, r*64+64) for both pixels ----
  const float* cx0 = xp0 + (size_t)(r << 6) * HW;
  const float* cx1 = xp1 + (size_t)(r << 6) * HW;
  u64 sl0 = 0, sl1 = 0;
  float mn0 = 1e30f, mn1 = 1e30f;
  #pragma unroll 8
  for (int cl = 0; cl < 64; ++cl) {
    float a = cx0[(size_t)cl * HW];
    float c = cx1[(size_t)cl * HW];
    sl0 |= (u64)(__float_as_uint(a) >> 31) << cl;
    sl1 |= (u64)(__float_as_uint(c) >> 31) << cl;
    mn0 = fminf(mn0, __builtin_fabsf(a));
    mn1 = fminf(mn1, __builtin_fabsf(c));
  }
  // butterfly allgather -> full sx[4] per pixel
  u64 sx0[4], sx1[4];
  {
    u64 pm = shfl_xor64(sl0, 1);
    u64 e0 = (r & 1) ? pm : sl0, e1 = (r & 1) ? sl0 : pm;
    u64 f0 = shfl_xor64(e0, 2),  f1 = shfl_xor64(e1, 2);
    sx0[0] = (r & 2) ? f0 : e0; sx0[1] = (r & 2) ? f1 : e1;
    sx0[2] = (r & 2) ? e0 : f0; sx0[3] = (r & 2) ? e1 : f1;
  }
  {
    u64 pm = shfl_xor64(sl1, 1);
    u64 e0 = (r & 1) ? pm : sl1, e1 = (r & 1) ? sl1 : pm;
    u64 f0 = shfl_xor64(e0, 2),  f1 = shfl_xor64(e1, 2);
    sx1[0] = (r & 2) ? f0 : e0; sx1[1] = (r & 2) ? f1 : e1;
    sx1[2] = (r & 2) ? e0 : f0; sx1[3] = (r & 2) ? e1 : f1;
  }
  mn0 = fminf(mn0, __shfl_xor(mn0, 1)); mn0 = fminf(mn0, __shfl_xor(mn0, 2));
  mn1 = fminf(mn1, __shfl_xor(mn1, 1)); mn1 = fminf(mn1, __shfl_xor(mn1, 2));

  // ---- layer 1: rows o = 4i+r (192 rows), both pixels per row read ----
  u64 ps0[12], ps1[12];
  #pragma unroll
  for (int wi = 0; wi < 12; ++wi) {
    u64 a0 = 0, a1 = 0;
    #pragma unroll 2
    for (int ii = 0; ii < 16; ++ii) {
      int o = (((wi << 4) | ii) << 2) | r;
      ulonglong2 wa = *(const ulonglong2*)&sw1[(size_t)(o << 2)];
      ulonglong2 wb = *(const ulonglong2*)&sw1[(size_t)(o << 2) + 2];
      int tv = st1[o];
      int p0 = __popcll(wa.x ^ sx0[0]) + __popcll(wa.y ^ sx0[1])
             + __popcll(wb.x ^ sx0[2]) + __popcll(wb.y ^ sx0[3]);
      int p1 = __popcll(wa.x ^ sx1[0]) + __popcll(wa.y ^ sx1[1])
             + __popcll(wb.x ^ sx1[2]) + __popcll(wb.y ^ sx1[3]);
      int sh = (ii << 2) | r;
      a0 |= (u64)(unsigned)((p0 + p0) > tv) << sh;
      a1 |= (u64)(unsigned)((p1 + p1) > tv) << sh;
    }
    ps0[wi] = a0; ps1[wi] = a1;
  }

  // rare exact-zero fixups (quad-uniform branches)
  if (mn0 == 0.0f) fix_px(cx0, sx0, ps0, r, sw1, st1);
  if (mn1 == 0.0f) fix_px(cx1, sx1, ps1, r, sw1, st1);

  // OR-allgather partial sign words -> full sy[12] per pixel
  #pragma unroll
  for (int wi = 0; wi < 12; ++wi) {
    u64 v0 = ps0[wi]; v0 |= shfl_xor64(v0, 1); v0 |= shfl_xor64(v0, 2); ps0[wi] = v0;
    u64 v1 = ps1[wi]; v1 |= shfl_xor64(v1, 1); v1 |= shfl_xor64(v1, 2); ps1[wi] = v1;
  }

  // ---- layer 2: rows o = 4j+r (64 rows), BN + residual + store ----
  #pragma unroll 2
  for (int j = 0; j < 64; ++j) {
    int o = (j << 2) | r;
    const u64* w = &sw2[(size_t)o * 12];
    ulonglong2 w0 = *(const ulonglong2*)(w + 0);
    ulonglong2 w1v = *(const ulonglong2*)(w + 2);
    ulonglong2 w2v = *(const ulonglong2*)(w + 4);
    ulonglong2 w3v = *(const ulonglong2*)(w + 6);
    ulonglong2 w4v = *(const ulonglong2*)(w + 8);
    ulonglong2 w5v = *(const ulonglong2*)(w + 10);
    float2 ab = sab2[o];
    int p0 = __popcll(w0.x ^ ps0[0])  + __popcll(w0.y ^ ps0[1])
           + __popcll(w1v.x ^ ps0[2]) + __popcll(w1v.y ^ ps0[3])
           + __popcll(w2v.x ^ ps0[4]) + __popcll(w2v.y ^ ps0[5])
           + __popcll(w3v.x ^ ps0[6]) + __popcll(w3v.y ^ ps0[7])
           + __popcll(w4v.x ^ ps0[8]) + __popcll(w4v.y ^ ps0[9])
           + __popcll(w5v.x ^ ps0[10]) + __popcll(w5v.y ^ ps0[11]);
    int p1 = __popcll(w0.x ^ ps1[0])  + __popcll(w0.y ^ ps1[1])
           + __popcll(w1v.x ^ ps1[2]) + __popcll(w1v.y ^ ps1[3])
           + __popcll(w2v.x ^ ps1[4]) + __popcll(w2v.y ^ ps1[5])
           + __popcll(w3v.x ^ ps1[6]) + __popcll(w3v.y ^ ps1[7])
           + __popcll(w4v.x ^ ps1[8]) + __popcll(w4v.y ^ ps1[9])
           + __popcll(w5v.x ^ ps1[10]) + __popcll(w5v.y ^ ps1[11]);
    float y0 = fmaf((float)p0, ab.x, ab.y);
    float y1 = fmaf((float)p1, ab.x, ab.y);
    op0[(size_t)o * HW] = y0 + xp0[(size_t)o * HW];
    op1[(size_t)o * HW] = y1 + xp1[(size_t)o * HW];
  }
}

extern "C" void kernel_launch(void* const* d_in, const int* in_sizes, int n_in,
                              void* d_out, int out_size, void* d_ws, size_t ws_size,
                              hipStream_t stream) {
  const float* x  = (const float*)d_in[0];
  const float* w1 = (const float*)d_in[1];
  const float* w2 = (const float*)d_in[2];
  const float* g1 = (const float*)d_in[3];
  const float* b1 = (const float*)d_in[4];
  const float* m1 = (const float*)d_in[5];
  const float* v1 = (const float*)d_in[6];
  const float* g2 = (const float*)d_in[7];
  const float* b2 = (const float*)d_in[8];
  const float* m2 = (const float*)d_in[9];
  const float* v2 = (const float*)d_in[10];
  float* out = (float*)d_out;

  u64*    pw1 = (u64*)d_ws;
  u64*    pw2 = pw1 + 3072;
  int*    t1  = (int*)(pw2 + 3072);
  float2* ab2 = (float2*)(t1 + CMID);

  prep_kernel<<<6160, 64, 0, stream>>>(w1, w2, g1, b1, m1, v1,
                                       g2, b2, m2, v2, pw1, pw2, t1, ab2);
  bnn_kernel<<<784, 256, 0, stream>>>(x, pw1, pw2, t1, ab2, out);
}